// Round 2
// baseline (651.387 us; speedup 1.0000x reference)
//
#include <hip/hip_runtime.h>
#include <hip/hip_cooperative_groups.h>
#include <math.h>

namespace cg = cooperative_groups;

// Problem shapes
#define SEQ  4096
#define DIM  300
#define NCLS 4
#define NB   128   // blocks; 32 seq rows per block, 8 per wave

// Workspace layout (float offsets)
#define OFF_P1   0
#define OFF_MID  (OFF_P1 + NB * DIM)
#define OFF_U    (OFF_MID + DIM)
#define OFF_SC   (OFF_U + DIM)
#define OFF_BMAX (OFF_SC + SEQ)
#define OFF_P2   (OFF_BMAX + NB)
// total ~= 319 KB of d_ws

// Single cooperative kernel: 6 phases separated by grid.sync().
// Phase work identical to the previous 6-kernel version; this removes 5
// dispatch gaps + 5 end-of-kernel drains from the timed graph.
__global__ __launch_bounds__(256) void fused_dan(
        const int* __restrict__ x, const float* __restrict__ emb,
        const float* __restrict__ W1, const float* __restrict__ b1,
        const float* __restrict__ Wb, const float* __restrict__ bb,
        const float* __restrict__ W2, const float* __restrict__ b2,
        float* __restrict__ out, float* __restrict__ ws) {
    cg::grid_group grid = cg::this_grid();

    float* P1     = ws + OFF_P1;
    float* MID    = ws + OFF_MID;
    float* U      = ws + OFF_U;
    float* SC     = ws + OFF_SC;
    float* BMAX   = ws + OFF_BMAX;
    float* P2     = ws + OFF_P2;
    float* reward = out + NCLS;

    __shared__ float lds[4][320];
    __shared__ float vec[DIM];
    __shared__ float red[4];

    const int wave = threadIdx.x >> 6, lane = threadIdx.x & 63;
    const int bid  = blockIdx.x;
    const int s0   = bid * 32 + wave * 8;

    // ---- P1: per-block partial sums of gathered rows (mean pooling) ----
    {
        float a0 = 0.f, a1 = 0.f, a2 = 0.f, a3 = 0.f, a4 = 0.f;
        #pragma unroll
        for (int r = 0; r < 8; ++r) {
            const float* row = emb + (size_t)x[s0 + r] * DIM;
            a0 += row[lane];
            a1 += row[lane + 64];
            a2 += row[lane + 128];
            a3 += row[lane + 192];
            if (lane < DIM - 256) a4 += row[lane + 256];
        }
        lds[wave][lane]       = a0;
        lds[wave][lane + 64]  = a1;
        lds[wave][lane + 128] = a2;
        lds[wave][lane + 192] = a3;
        lds[wave][lane + 256] = a4;  // lanes>=44 store junk; never read (d<300)
        __syncthreads();
        for (int d = threadIdx.x; d < DIM; d += 256)
            P1[bid * DIM + d] = lds[0][d] + lds[1][d] + lds[2][d] + lds[3][d];
    }
    grid.sync();

    // ---- P2: dense = sum(P1)/SEQ; mid = W1@dense + b1 (blocks 0..74) ----
    if (bid < 75) {
        for (int d = threadIdx.x; d < DIM; d += 256) {
            float s = 0.f;
            for (int b = 0; b < NB; ++b) s += P1[b * DIM + d];
            vec[d] = s * (1.0f / (float)SEQ);
        }
        __syncthreads();
        const int i    = bid * 4 + wave;  // [0,300)
        const float* w = W1 + (size_t)i * DIM;
        float s = w[lane] * vec[lane] + w[lane + 64] * vec[lane + 64]
                + w[lane + 128] * vec[lane + 128]
                + w[lane + 192] * vec[lane + 192];
        if (lane < DIM - 256) s += w[lane + 256] * vec[lane + 256];
        for (int off = 32; off; off >>= 1) s += __shfl_down(s, off);
        if (lane == 0) MID[i] = s + b1[i];
    }
    grid.sync();

    // ---- P3: u = Wb @ mid (blocks 0..74) ----
    if (bid < 75) {
        for (int d = threadIdx.x; d < DIM; d += 256) vec[d] = MID[d];
        __syncthreads();
        const int i    = bid * 4 + wave;
        const float* w = Wb + (size_t)i * DIM;
        float s = w[lane] * vec[lane] + w[lane + 64] * vec[lane + 64]
                + w[lane + 128] * vec[lane + 128]
                + w[lane + 192] * vec[lane + 192];
        if (lane < DIM - 256) s += w[lane + 256] * vec[lane + 256];
        for (int off = 32; off; off >>= 1) s += __shfl_down(s, off);
        if (lane == 0) U[i] = s;
    }
    grid.sync();

    // ---- P4: scores[s] = embed[s].u + bb; per-block max ----
    {
        const float u0 = U[lane], u1 = U[lane + 64], u2 = U[lane + 128],
                    u3 = U[lane + 192];
        const float u4  = (lane < DIM - 256) ? U[lane + 256] : 0.f;
        const float bbv = bb[0];
        float wmax = -1e30f;
        #pragma unroll
        for (int r = 0; r < 8; ++r) {
            const float* row = emb + (size_t)x[s0 + r] * DIM;
            float s = row[lane] * u0 + row[lane + 64] * u1
                    + row[lane + 128] * u2 + row[lane + 192] * u3;
            if (lane < DIM - 256) s += row[lane + 256] * u4;
            for (int off = 32; off; off >>= 1) s += __shfl_down(s, off);
            if (lane == 0) {
                s += bbv;
                SC[s0 + r] = s;
                wmax = fmaxf(wmax, s);
            }
        }
        if (lane == 0) red[wave] = wmax;
        __syncthreads();
        if (threadIdx.x == 0)
            BMAX[bid] =
                fmaxf(fmaxf(red[0], red[1]), fmaxf(red[2], red[3]));
    }
    grid.sync();

    // ---- P5: softmax (redundant per-block) + weighted partial pooling ----
    {
        float m = -1e30f;
        for (int i = threadIdx.x; i < NB; i += 256) m = fmaxf(m, BMAX[i]);
        for (int off = 32; off; off >>= 1) m = fmaxf(m, __shfl_down(m, off));
        if (lane == 0) red[wave] = m;
        __syncthreads();
        const float mx = fmaxf(fmaxf(red[0], red[1]), fmaxf(red[2], red[3]));
        __syncthreads();
        float s = 0.f;
        for (int i = threadIdx.x; i < SEQ; i += 256) s += expf(SC[i] - mx);
        for (int off = 32; off; off >>= 1) s += __shfl_down(s, off);
        if (lane == 0) red[wave] = s;
        __syncthreads();
        const float inv = 1.0f / (red[0] + red[1] + red[2] + red[3]);

        float a0 = 0.f, a1 = 0.f, a2 = 0.f, a3 = 0.f, a4 = 0.f;
        #pragma unroll
        for (int r = 0; r < 8; ++r) {
            const int srow = s0 + r;
            const float rw = expf(SC[srow] - mx) * inv;
            if (lane == 0) reward[srow] = rw;
            const float* row = emb + (size_t)x[srow] * DIM;
            a0 += rw * row[lane];
            a1 += rw * row[lane + 64];
            a2 += rw * row[lane + 128];
            a3 += rw * row[lane + 192];
            if (lane < DIM - 256) a4 += rw * row[lane + 256];
        }
        lds[wave][lane]       = a0;
        lds[wave][lane + 64]  = a1;
        lds[wave][lane + 128] = a2;
        lds[wave][lane + 192] = a3;
        lds[wave][lane + 256] = a4;
        __syncthreads();
        for (int d = threadIdx.x; d < DIM; d += 256)
            P2[bid * DIM + d] = lds[0][d] + lds[1][d] + lds[2][d] + lds[3][d];
    }
    grid.sync();

    // ---- P6: addition = sum(P2)/SEQ; out = W2@(mid+addition) + b2 ----
    if (bid == 0) {
        for (int d = threadIdx.x; d < DIM; d += 256) {
            float s = 0.f;
            for (int b = 0; b < NB; ++b) s += P2[b * DIM + d];
            vec[d] = MID[d] + s * (1.0f / (float)SEQ);
        }
        __syncthreads();
        const float* w = W2 + (size_t)wave * DIM;  // wave = class [0,4)
        float s = w[lane] * vec[lane] + w[lane + 64] * vec[lane + 64]
                + w[lane + 128] * vec[lane + 128]
                + w[lane + 192] * vec[lane + 192];
        if (lane < DIM - 256) s += w[lane + 256] * vec[lane + 256];
        for (int off = 32; off; off >>= 1) s += __shfl_down(s, off);
        if (lane == 0) out[wave] = s + b2[wave];
    }
}

// --------------------------------------------------------------------------
extern "C" void kernel_launch(void* const* d_in, const int* in_sizes, int n_in,
                              void* d_out, int out_size, void* d_ws,
                              size_t ws_size, hipStream_t stream) {
    const int*   x   = (const int*)d_in[0];
    const float* emb = (const float*)d_in[1];
    const float* W1  = (const float*)d_in[2];
    const float* b1  = (const float*)d_in[3];
    const float* Wb  = (const float*)d_in[4];
    const float* bb  = (const float*)d_in[5];
    const float* W2  = (const float*)d_in[6];
    const float* b2  = (const float*)d_in[7];
    float* out = (float*)d_out;
    float* ws  = (float*)d_ws;

    void* args[] = {(void*)&x,  (void*)&emb, (void*)&W1, (void*)&b1,
                    (void*)&Wb, (void*)&bb,  (void*)&W2, (void*)&b2,
                    (void*)&out, (void*)&ws};
    hipLaunchCooperativeKernel((void*)fused_dan, dim3(NB), dim3(256), args, 0,
                               stream);
}

// Round 3
// 576.448 us; speedup vs baseline: 1.1300x; 1.1300x over previous
//
#include <hip/hip_runtime.h>
#include <math.h>

// Problem shapes
#define SEQ  4096
#define DIM  300
#define NCLS 4
#define NB   128            // gather blocks; 32 seq rows each, 8 per wave
#define NCH  75             // float4 chunks per row (300/4)
#define INV_S (1.0f / 4096.0f)

// Workspace layout (float offsets; all float4-aligned since 300 % 4 == 0)
#define OFF_P1   0                      // [NB*DIM]  mean-pool partials
#define OFF_MID  (OFF_P1 + NB * DIM)    // [DIM]
#define OFF_U    (OFF_MID + DIM)        // [DIM]
#define OFF_P2   (OFF_U + DIM)          // [NB*DIM]  weighted-pool partials
#define OFF_ZP   (OFF_P2 + NB * DIM)    // [NB]      partial exp-sums
#define OFF_CNT  (OFF_ZP + NB)          // [1]       block-completion counter

__device__ __forceinline__ float dot4(float4 a, float4 b) {
    return a.x * b.x + a.y * b.y + a.z * b.z + a.w * b.w;
}

// --------------------------------------------------------------------------
// K1: per-block partial sums of gathered embedding rows (mean pooling).
// Also zeroes the completion counter used by K3 (ws is poisoned each iter).
__global__ __launch_bounds__(256) void k_gather_sum(
        const int* __restrict__ x, const float* __restrict__ emb,
        float* __restrict__ ws) {
    float* P1 = ws + OFF_P1;
    if (blockIdx.x == 0 && threadIdx.x == 0) *(int*)(ws + OFF_CNT) = 0;
    __shared__ float4 lds4[4][80];
    const int wave = threadIdx.x >> 6, lane = threadIdx.x & 63;
    float4 aa = {0.f, 0.f, 0.f, 0.f}, ab = {0.f, 0.f, 0.f, 0.f};
    const int s0 = blockIdx.x * 32 + wave * 8;
    #pragma unroll
    for (int r = 0; r < 8; ++r) {
        const float4* row = (const float4*)(emb + (size_t)x[s0 + r] * DIM);
        float4 ra = row[lane];
        aa.x += ra.x; aa.y += ra.y; aa.z += ra.z; aa.w += ra.w;
        if (lane < NCH - 64) {
            float4 rb = row[64 + lane];
            ab.x += rb.x; ab.y += rb.y; ab.z += rb.z; ab.w += rb.w;
        }
    }
    lds4[wave][lane] = aa;
    if (lane < NCH - 64) lds4[wave][64 + lane] = ab;
    __syncthreads();
    for (int c = threadIdx.x; c < NCH; c += 256) {
        float4 a = lds4[0][c], b = lds4[1][c], d = lds4[2][c], e = lds4[3][c];
        float4 v;
        v.x = a.x + b.x + d.x + e.x;
        v.y = a.y + b.y + d.y + e.y;
        v.z = a.z + b.z + d.z + e.z;
        v.w = a.w + b.w + d.w + e.w;
        ((float4*)P1)[blockIdx.x * NCH + c] = v;
    }
}

// --------------------------------------------------------------------------
// K2 (75 blocks): dense = sum(P1)/SEQ (redundant per block), FULL mid in LDS
// (redundant per block; 360 KB W1 re-read x75 = 27 MB L2, ~1 us total),
// then each block's 4 waves emit 4 rows of u = Wb @ mid. Block 0 writes mid.
__global__ __launch_bounds__(256) void k_mid_u(
        const float* __restrict__ W1, const float* __restrict__ b1,
        const float* __restrict__ Wb, float* __restrict__ ws) {
    const float* P1 = ws + OFF_P1;
    float* MID = ws + OFF_MID;
    float* U   = ws + OFF_U;
    __shared__ float vec[304];   // dense
    __shared__ float midv[304];  // full mid
    const int tid = threadIdx.x;

    for (int c = tid; c < NCH; c += 256) {
        float4 s = {0.f, 0.f, 0.f, 0.f};
        const float4* p = (const float4*)P1;
        for (int b = 0; b < NB; ++b) {
            float4 t = p[b * NCH + c];
            s.x += t.x; s.y += t.y; s.z += t.z; s.w += t.w;
        }
        float4 v = {s.x * INV_S, s.y * INV_S, s.z * INV_S, s.w * INV_S};
        ((float4*)vec)[c] = v;
    }
    __syncthreads();

    for (int i = tid; i < DIM; i += 256) {
        const float4* w = (const float4*)(W1 + (size_t)i * DIM);
        float m = 0.f;
        for (int c = 0; c < NCH; ++c) m += dot4(w[c], ((float4*)vec)[c]);
        midv[i] = m + b1[i];
    }
    __syncthreads();

    if (blockIdx.x == 0)
        for (int c = tid; c < NCH; c += 256)
            ((float4*)MID)[c] = ((float4*)midv)[c];

    const int wave = tid >> 6, lane = tid & 63;
    const int i = blockIdx.x * 4 + wave;  // [0,300)
    const float4* w  = (const float4*)(Wb + (size_t)i * DIM);
    const float4* mv = (const float4*)midv;
    float s = dot4(w[lane], mv[lane]);
    if (lane < NCH - 64) s += dot4(w[64 + lane], mv[64 + lane]);
    for (int off = 32; off; off >>= 1) s += __shfl_down(s, off);
    if (lane == 0) U[i] = s;
}

// --------------------------------------------------------------------------
// K3 (128 blocks): single gather pass computes score_s = e_s.u + bb, then
// REUSES the row registers for the unnormalized weighted pool (w = exp(sc),
// no max-subtract: scores are ~1e-3, exp ~= 1.0). Writes w into reward slots,
// partial Z and partial pooled sums. The LAST block to finish (fence +
// atomic counter) reduces Z and P2, rescales reward by 1/Z, and computes the
// 4-class output — no extra launch.
__global__ __launch_bounds__(256) void k_score_pool(
        const int* __restrict__ x, const float* __restrict__ emb,
        const float* __restrict__ bb, const float* __restrict__ W2,
        const float* __restrict__ b2, float* __restrict__ out,
        float* __restrict__ ws) {
    const float* MID = ws + OFF_MID;
    const float* U   = ws + OFF_U;
    float* P2  = ws + OFF_P2;
    float* ZP  = ws + OFF_ZP;
    int*   cnt = (int*)(ws + OFF_CNT);
    float* reward = out + NCLS;

    __shared__ float4 lds4[4][80];
    __shared__ float red[4];
    __shared__ float vecE[304];
    __shared__ int last;

    const int wave = threadIdx.x >> 6, lane = threadIdx.x & 63;
    const float4* U4 = (const float4*)U;
    const float4 ua = U4[lane];
    const float4 ub = (lane < NCH - 64) ? U4[64 + lane]
                                        : make_float4(0.f, 0.f, 0.f, 0.f);
    const float bbv = bb[0];

    float4 aa = {0.f, 0.f, 0.f, 0.f}, ab = {0.f, 0.f, 0.f, 0.f};
    float zp = 0.f;
    const int s0 = blockIdx.x * 32 + wave * 8;
    #pragma unroll
    for (int r = 0; r < 8; ++r) {
        const int srow = s0 + r;
        const float4* row = (const float4*)(emb + (size_t)x[srow] * DIM);
        const float4 ra = row[lane];
        const float4 rb = (lane < NCH - 64) ? row[64 + lane]
                                            : make_float4(0.f, 0.f, 0.f, 0.f);
        float s = dot4(ra, ua) + dot4(rb, ub);
        for (int off = 32; off; off >>= 1) s += __shfl_down(s, off);
        s = __shfl(s, 0);
        const float w = expf(s + bbv);
        if (lane == 0) reward[srow] = w;  // unnormalized; rescaled below
        zp += w;
        aa.x += w * ra.x; aa.y += w * ra.y; aa.z += w * ra.z; aa.w += w * ra.w;
        ab.x += w * rb.x; ab.y += w * rb.y; ab.z += w * rb.z; ab.w += w * rb.w;
    }
    lds4[wave][lane] = aa;
    if (lane < NCH - 64) lds4[wave][64 + lane] = ab;
    if (lane == 0) red[wave] = zp;
    __syncthreads();
    for (int c = threadIdx.x; c < NCH; c += 256) {
        float4 a = lds4[0][c], b = lds4[1][c], d = lds4[2][c], e = lds4[3][c];
        float4 v;
        v.x = a.x + b.x + d.x + e.x;
        v.y = a.y + b.y + d.y + e.y;
        v.z = a.z + b.z + d.z + e.z;
        v.w = a.w + b.w + d.w + e.w;
        ((float4*)P2)[blockIdx.x * NCH + c] = v;
    }
    if (threadIdx.x == 0)
        ZP[blockIdx.x] = red[0] + red[1] + red[2] + red[3];

    // ---- completion handshake ----
    __threadfence();           // make this block's P2/ZP/reward visible
    __syncthreads();
    if (threadIdx.x == 0) last = (atomicAdd(cnt, 1) == NB - 1);
    __syncthreads();
    if (!last) return;
    __threadfence();           // acquire all other blocks' writes

    // ---- epilogue (one block) ----
    float z = 0.f;
    for (int i = threadIdx.x; i < NB; i += 256) z += ZP[i];
    for (int off = 32; off; off >>= 1) z += __shfl_down(z, off);
    if (lane == 0) red[wave] = z;
    __syncthreads();
    const float Z = red[0] + red[1] + red[2] + red[3];
    const float invZ = 1.0f / Z;

    for (int i = threadIdx.x; i < SEQ; i += 256) reward[i] *= invZ;

    const float scale = invZ * INV_S;
    for (int c = threadIdx.x; c < NCH; c += 256) {
        float4 s = {0.f, 0.f, 0.f, 0.f};
        const float4* p = (const float4*)P2;
        for (int b = 0; b < NB; ++b) {
            float4 t = p[b * NCH + c];
            s.x += t.x; s.y += t.y; s.z += t.z; s.w += t.w;
        }
        float4 m = ((const float4*)MID)[c];
        float4 v = {m.x + s.x * scale, m.y + s.y * scale,
                    m.z + s.z * scale, m.w + s.w * scale};
        ((float4*)vecE)[c] = v;
    }
    __syncthreads();

    const float4* w  = (const float4*)(W2 + (size_t)wave * DIM);  // wave=class
    const float4* ve = (const float4*)vecE;
    float s = dot4(w[lane], ve[lane]);
    if (lane < NCH - 64) s += dot4(w[64 + lane], ve[64 + lane]);
    for (int off = 32; off; off >>= 1) s += __shfl_down(s, off);
    if (lane == 0) out[wave] = s + b2[wave];
}

// --------------------------------------------------------------------------
extern "C" void kernel_launch(void* const* d_in, const int* in_sizes, int n_in,
                              void* d_out, int out_size, void* d_ws,
                              size_t ws_size, hipStream_t stream) {
    const int*   x   = (const int*)d_in[0];
    const float* emb = (const float*)d_in[1];
    const float* W1  = (const float*)d_in[2];
    const float* b1  = (const float*)d_in[3];
    const float* Wb  = (const float*)d_in[4];
    const float* bb  = (const float*)d_in[5];
    const float* W2  = (const float*)d_in[6];
    const float* b2  = (const float*)d_in[7];
    float* out = (float*)d_out;
    float* ws  = (float*)d_ws;

    k_gather_sum<<<NB, 256, 0, stream>>>(x, emb, ws);
    k_mid_u<<<75, 256, 0, stream>>>(W1, b1, Wb, ws);
    k_score_pool<<<NB, 256, 0, stream>>>(x, emb, bb, W2, b2, out, ws);
}